// Round 2
// baseline (735.814 us; speedup 1.0000x reference)
//
#include <hip/hip_runtime.h>
#include <stdint.h>

#define B_   4
#define S_   2048
#define H_   16
#define DK_  64
#define DM_  1024
#define M_   (B_ * S_)   // 8192

typedef __attribute__((ext_vector_type(4))) float f32x4;
typedef __attribute__((ext_vector_type(8))) short s16x8;

__device__ __forceinline__ uint16_t f2bf(float f) {
    union { float f; uint32_t u; } v; v.f = f;
    uint32_t u = v.u;
    uint32_t r = (u + 0x7FFFu + ((u >> 16) & 1u)) >> 16;  // RNE
    return (uint16_t)r;
}
__device__ __forceinline__ float bf2f(uint16_t h) {
    union { uint32_t u; float f; } v; v.u = ((uint32_t)h) << 16;
    return v.f;
}

// ---------------- fp32 -> bf16 convert (n divisible by 4) ----------------
__global__ __launch_bounds__(256) void cvt_bf16(const float* __restrict__ in,
                                                uint16_t* __restrict__ out, int n) {
    int i = (blockIdx.x * 256 + threadIdx.x) * 4;
    if (i >= n) return;
    float4 v = *reinterpret_cast<const float4*>(in + i);
    ushort4 o;
    o.x = f2bf(v.x); o.y = f2bf(v.y); o.z = f2bf(v.z); o.w = f2bf(v.w);
    *reinterpret_cast<ushort4*>(out + i) = o;
}

// ---------------- generic bf16 GEMM: C = A(MxK) * B(NxK)^T ----------------
// MODE 0: C fp32 row-major (MxN)
// MODE 1: C bf16, scatter to (b,h,s,dk)  [for Q,K]
// MODE 2: C bf16, scatter to (b,h,dk,s)  [for V transposed]
template <int MODE>
__global__ __launch_bounds__(256) void gemm_bt(const uint16_t* __restrict__ A,
                                               const uint16_t* __restrict__ Bm,
                                               void* __restrict__ Cout,
                                               int M, int N, int K) {
    const int lane = threadIdx.x & 63;
    const int w    = threadIdx.x >> 6;
    const int wr   = w >> 1, wc = w & 1;       // 2x2 waves -> 128x128 block tile
    const int m0   = blockIdx.x * 128 + wr * 64;
    const int n0   = blockIdx.y * 128 + wc * 64;
    const int lr   = lane & 15;                // row (A) / col (B,D) within fragment
    const int lg   = lane >> 4;                // k-group

    f32x4 acc[4][4] = {};
    const uint16_t* Ap = A  + (size_t)(m0 + lr) * K + lg * 8;
    const uint16_t* Bp = Bm + (size_t)(n0 + lr) * K + lg * 8;

    for (int k0 = 0; k0 < K; k0 += 32) {
        s16x8 af[4], bfr[4];
#pragma unroll
        for (int i = 0; i < 4; ++i)
            af[i] = *reinterpret_cast<const s16x8*>(Ap + (size_t)i * 16 * K + k0);
#pragma unroll
        for (int j = 0; j < 4; ++j)
            bfr[j] = *reinterpret_cast<const s16x8*>(Bp + (size_t)j * 16 * K + k0);
#pragma unroll
        for (int i = 0; i < 4; ++i)
#pragma unroll
            for (int j = 0; j < 4; ++j)
                acc[i][j] = __builtin_amdgcn_mfma_f32_16x16x32_bf16(af[i], bfr[j],
                                                                    acc[i][j], 0, 0, 0);
    }

#pragma unroll
    for (int i = 0; i < 4; ++i)
#pragma unroll
        for (int j = 0; j < 4; ++j)
#pragma unroll
            for (int r = 0; r < 4; ++r) {
                int row = m0 + i * 16 + lg * 4 + r;   // D: row=(lane>>4)*4+reg
                int col = n0 + j * 16 + lr;           // D: col=lane&15
                float v = acc[i][j][r];
                if constexpr (MODE == 0) {
                    ((float*)Cout)[(size_t)row * N + col] = v;
                } else {
                    int b = row >> 11, s = row & (S_ - 1);
                    int h = col >> 6,  dk = col & 63;
                    if constexpr (MODE == 1) {
                        ((uint16_t*)Cout)[(((size_t)(b * H_ + h)) * S_ + s) * DK_ + dk] = f2bf(v);
                    } else {
                        ((uint16_t*)Cout)[(((size_t)(b * H_ + h)) * DK_ + dk) * S_ + s] = f2bf(v);
                    }
                }
            }
}

// ---------------- RoPE over contiguous q||k region, one pair/thread ----------------
__global__ __launch_bounds__(256) void rope_kernel(uint16_t* __restrict__ a,
                                                   const int* __restrict__ pos,
                                                   int npairs) {
    int t = blockIdx.x * 256 + threadIdx.x;
    if (t >= npairs) return;
    int j = t & 31;
    int s = (t >> 5) & (S_ - 1);
    float p   = (float)pos[s];
    // inv_freq = theta^(-j/32) = exp2(-j * log2(10000)/32)
    float inv = exp2f(-(float)j * (13.287712379549449f / 32.0f));
    float ang = p * inv;
    float sn, c;
    sincosf(ang, &sn, &c);
    uint32_t pr = *reinterpret_cast<uint32_t*>(a + (size_t)2 * t);
    float x0 = bf2f((uint16_t)(pr & 0xFFFF));
    float x1 = bf2f((uint16_t)(pr >> 16));
    float r0 = x0 * c - x1 * sn;
    float r1 = x0 * sn + x1 * c;
    uint32_t ot = (uint32_t)f2bf(r0) | ((uint32_t)f2bf(r1) << 16);
    *reinterpret_cast<uint32_t*>(a + (size_t)2 * t) = ot;
}

// ---------------- causal flash attention ----------------
// grid (32 qtiles, 64 bh), 4 waves/block, each wave owns 16 q-rows. k-tile = 32.
__global__ __launch_bounds__(256) void flash_attn(const uint16_t* __restrict__ q,
                                                  const uint16_t* __restrict__ k,
                                                  const uint16_t* __restrict__ vt,
                                                  uint16_t* __restrict__ attn) {
    __shared__ uint16_t pbuf[4][16][32];   // per-wave private P staging
    const int lane = threadIdx.x & 63;
    const int w    = threadIdx.x >> 6;
    const int lr   = lane & 15, lg = lane >> 4;
    const int bh   = blockIdx.y;
    const int q0   = blockIdx.x * 64 + w * 16;

    const uint16_t* qb = q  + ((size_t)bh * S_ + q0) * DK_;
    const uint16_t* kb = k  + (size_t)bh * S_ * DK_;
    const uint16_t* vb = vt + (size_t)bh * DK_ * S_;

    s16x8 qf[2];
    qf[0] = *reinterpret_cast<const s16x8*>(qb + (size_t)lr * DK_ + lg * 8);
    qf[1] = *reinterpret_cast<const s16x8*>(qb + (size_t)lr * DK_ + 32 + lg * 8);

    f32x4 o[4] = {};
    float mrow[4], lrow[4];
#pragma unroll
    for (int r = 0; r < 4; ++r) { mrow[r] = -1e30f; lrow[r] = 0.f; }

    const int kend = q0 + 16;
    for (int kt = 0; kt < kend; kt += 32) {
        f32x4 sc[2] = {};
#pragma unroll
        for (int ct = 0; ct < 2; ++ct) {
            const uint16_t* kp = kb + (size_t)(kt + ct * 16 + lr) * DK_ + lg * 8;
            s16x8 kf0 = *reinterpret_cast<const s16x8*>(kp);
            s16x8 kf1 = *reinterpret_cast<const s16x8*>(kp + 32);
            sc[ct] = __builtin_amdgcn_mfma_f32_16x16x32_bf16(qf[0], kf0, sc[ct], 0, 0, 0);
            sc[ct] = __builtin_amdgcn_mfma_f32_16x16x32_bf16(qf[1], kf1, sc[ct], 0, 0, 0);
        }

        const bool need_mask = (kt + 31 > q0);
        float sv[2][4];
#pragma unroll
        for (int ct = 0; ct < 2; ++ct)
#pragma unroll
            for (int r = 0; r < 4; ++r) {
                float v = sc[ct][r] * 0.125f;   // 1/sqrt(64)
                if (need_mask) {
                    int colg = kt + ct * 16 + lr;
                    int rowg = q0 + lg * 4 + r;
                    if (colg > rowg) v = -1e30f;
                }
                sv[ct][r] = v;
            }

        // online softmax (reduce over 16-lane col groups)
#pragma unroll
        for (int r = 0; r < 4; ++r) {
            float tm = fmaxf(sv[0][r], sv[1][r]);
#pragma unroll
            for (int off = 1; off < 16; off <<= 1)
                tm = fmaxf(tm, __shfl_xor(tm, off));
            float mnew  = fmaxf(mrow[r], tm);
            float alpha = __expf(mrow[r] - mnew);
            mrow[r] = mnew;
            float p0 = __expf(sv[0][r] - mnew);
            float p1 = __expf(sv[1][r] - mnew);
            float ps = p0 + p1;
#pragma unroll
            for (int off = 1; off < 16; off <<= 1)
                ps += __shfl_xor(ps, off);
            lrow[r] = lrow[r] * alpha + ps;
#pragma unroll
            for (int j = 0; j < 4; ++j) o[j][r] *= alpha;
            pbuf[w][lg * 4 + r][lr]      = f2bf(p0);
            pbuf[w][lg * 4 + r][16 + lr] = f2bf(p1);
        }

        // PV: A = P fragment from LDS (same-wave DS ops are ordered)
        s16x8 pa = *reinterpret_cast<const s16x8*>(&pbuf[w][lr][lg * 8]);
#pragma unroll
        for (int j = 0; j < 4; ++j) {
            s16x8 vf = *reinterpret_cast<const s16x8*>(vb + (size_t)(j * 16 + lr) * S_ + kt + lg * 8);
            o[j] = __builtin_amdgcn_mfma_f32_16x16x32_bf16(pa, vf, o[j], 0, 0, 0);
        }
    }

    const int b = bh >> 4, h = bh & 15;
#pragma unroll
    for (int j = 0; j < 4; ++j)
#pragma unroll
        for (int r = 0; r < 4; ++r) {
            int sg = q0 + lg * 4 + r;
            float v = o[j][r] / lrow[r];
            attn[((size_t)b * S_ + sg) * DM_ + h * 64 + j * 16 + lr] = f2bf(v);
        }
}

extern "C" void kernel_launch(void* const* d_in, const int* in_sizes, int n_in,
                              void* d_out, int out_size, void* d_ws, size_t ws_size,
                              hipStream_t stream) {
    (void)in_sizes; (void)n_in; (void)out_size;
    const float* x   = (const float*)d_in[0];
    const float* wq  = (const float*)d_in[1];
    const float* wk  = (const float*)d_in[2];
    const float* wv  = (const float*)d_in[3];
    const float* wo  = (const float*)d_in[4];
    const int* tpos  = (const int*)d_in[5];
    float* out = (float*)d_out;

    const size_t NX = (size_t)M_ * DM_;   // 8388608
    const size_t NW = (size_t)DM_ * DM_;  // 1048576
    const size_t need = (NX + 4 * NW + 4 * NX) * sizeof(uint16_t);
    if (ws_size < need) return;  // fail loudly via wrong output

    uint16_t* ws  = (uint16_t*)d_ws;
    uint16_t* xb  = ws;
    uint16_t* wqb = xb + NX;
    uint16_t* wkb = wqb + NW;
    uint16_t* wvb = wkb + NW;
    uint16_t* wob = wvb + NW;
    uint16_t* qb  = wob + NW;
    uint16_t* kb  = qb + NX;    // contiguous with qb (rope covers both)
    uint16_t* vtb = kb + NX;
    uint16_t* ab  = vtb + NX;

    cvt_bf16<<<(int)(NX / 1024), 256, 0, stream>>>(x, xb, (int)NX);
    cvt_bf16<<<(int)(NW / 1024), 256, 0, stream>>>(wq, wqb, (int)NW);
    cvt_bf16<<<(int)(NW / 1024), 256, 0, stream>>>(wk, wkb, (int)NW);
    cvt_bf16<<<(int)(NW / 1024), 256, 0, stream>>>(wv, wvb, (int)NW);
    cvt_bf16<<<(int)(NW / 1024), 256, 0, stream>>>(wo, wob, (int)NW);

    dim3 g(M_ / 128, DM_ / 128), blk(256);
    gemm_bt<1><<<g, blk, 0, stream>>>(xb, wqb, qb,  M_, DM_, DM_);
    gemm_bt<1><<<g, blk, 0, stream>>>(xb, wkb, kb,  M_, DM_, DM_);
    gemm_bt<2><<<g, blk, 0, stream>>>(xb, wvb, vtb, M_, DM_, DM_);

    int npairs = 2 * B_ * H_ * S_ * (DK_ / 2);   // q and k together
    rope_kernel<<<npairs / 256, 256, 0, stream>>>(qb, tpos, npairs);

    flash_attn<<<dim3(S_ / 64, B_ * H_), 256, 0, stream>>>(qb, kb, vtb, ab);

    gemm_bt<0><<<g, blk, 0, stream>>>(ab, wob, out, M_, DM_, DM_);
}

// Round 3
// 392.840 us; speedup vs baseline: 1.8731x; 1.8731x over previous
//
#include <hip/hip_runtime.h>
#include <stdint.h>

#define B_   4
#define S_   2048
#define H_   16
#define DK_  64
#define DM_  1024
#define M_   (B_ * S_)   // 8192

typedef __attribute__((ext_vector_type(4))) float f32x4;
typedef __attribute__((ext_vector_type(8))) short s16x8;

__device__ __forceinline__ uint16_t f2bf(float f) {
    union { float f; uint32_t u; } v; v.f = f;
    uint32_t u = v.u;
    uint32_t r = (u + 0x7FFFu + ((u >> 16) & 1u)) >> 16;  // RNE
    return (uint16_t)r;
}
__device__ __forceinline__ float bf2f(uint16_t h) {
    union { uint32_t u; float f; } v; v.u = ((uint32_t)h) << 16;
    return v.f;
}

// async global->LDS, 16B per lane; lds base must be wave-uniform
__device__ __forceinline__ void gload_lds16(const uint16_t* g, uint16_t* l) {
    __builtin_amdgcn_global_load_lds(
        (const __attribute__((address_space(1))) void*)g,
        (__attribute__((address_space(3))) void*)l, 16, 0, 0);
}

// ---------------- fp32 -> bf16 convert (n divisible by 4) ----------------
__global__ __launch_bounds__(256) void cvt_bf16(const float* __restrict__ in,
                                                uint16_t* __restrict__ out, int n) {
    int i = (blockIdx.x * 256 + threadIdx.x) * 4;
    if (i >= n) return;
    float4 v = *reinterpret_cast<const float4*>(in + i);
    ushort4 o;
    o.x = f2bf(v.x); o.y = f2bf(v.y); o.z = f2bf(v.z); o.w = f2bf(v.w);
    *reinterpret_cast<ushort4*>(out + i) = o;
}

// ---------------- bf16 GEMM: C = A(MxK) * B(NxK)^T, m97-style LDS staging ----------------
// MODE 0: C fp32 row-major (MxN)
// MODE 1: C bf16, scatter to (b,h,s,dk)  [for Q,K]
// MODE 2: C bf16, scatter to (b,h,dk,s)  [for V transposed]
template <int MODE>
__global__ __launch_bounds__(256) void gemm_bt(const uint16_t* __restrict__ A,
                                               const uint16_t* __restrict__ Bm,
                                               void* __restrict__ Cout,
                                               int M, int N, int K) {
    __shared__ uint16_t Al[128 * 32];
    __shared__ uint16_t Bl[128 * 32];
    const int lane = threadIdx.x & 63;
    const int w    = threadIdx.x >> 6;
    const int wr   = w >> 1, wc = w & 1;       // 2x2 waves -> 128x128 block tile
    const int m0   = blockIdx.x * 128;
    const int n0   = blockIdx.y * 128;
    const int lr   = lane & 15;
    const int lg   = lane >> 4;

    // staging: wave w covers rows [w*32, w*32+32) of each 128x32 tile.
    // instr i in {0,1}: rows w*32+i*16 + lane/4, col elems (lane&3)*8
    const int srow = w * 32 + (lane >> 2);
    const int scol = (lane & 3) * 8;
    const uint16_t* Ag = A  + (size_t)(m0 + srow) * K + scol;
    const uint16_t* Bg = Bm + (size_t)(n0 + srow) * K + scol;
    uint16_t* Ald = Al + (size_t)(w * 32) * 32;   // wave-uniform LDS bases
    uint16_t* Bld = Bl + (size_t)(w * 32) * 32;

    f32x4 acc[4][4] = {};
    for (int k0 = 0; k0 < K; k0 += 32) {
        gload_lds16(Ag + k0,            Ald);
        gload_lds16(Ag + 16 * (size_t)K + k0, Ald + 16 * 32);
        gload_lds16(Bg + k0,            Bld);
        gload_lds16(Bg + 16 * (size_t)K + k0, Bld + 16 * 32);
        __syncthreads();
        s16x8 af[4], bfr[4];
#pragma unroll
        for (int i = 0; i < 4; ++i)
            af[i] = *reinterpret_cast<const s16x8*>(&Al[(wr * 64 + i * 16 + lr) * 32 + lg * 8]);
#pragma unroll
        for (int j = 0; j < 4; ++j)
            bfr[j] = *reinterpret_cast<const s16x8*>(&Bl[(wc * 64 + j * 16 + lr) * 32 + lg * 8]);
#pragma unroll
        for (int i = 0; i < 4; ++i)
#pragma unroll
            for (int j = 0; j < 4; ++j)
                acc[i][j] = __builtin_amdgcn_mfma_f32_16x16x32_bf16(af[i], bfr[j],
                                                                    acc[i][j], 0, 0, 0);
        __syncthreads();
    }

#pragma unroll
    for (int i = 0; i < 4; ++i)
#pragma unroll
        for (int j = 0; j < 4; ++j)
#pragma unroll
            for (int r = 0; r < 4; ++r) {
                int row = wr * 64 + m0 + i * 16 + lg * 4 + r;
                int col = wc * 64 + n0 + j * 16 + lr;
                float v = acc[i][j][r];
                if constexpr (MODE == 0) {
                    ((float*)Cout)[(size_t)row * N + col] = v;
                } else {
                    int b = row >> 11, s = row & (S_ - 1);
                    int h = col >> 6,  dk = col & 63;
                    if constexpr (MODE == 1) {
                        ((uint16_t*)Cout)[(((size_t)(b * H_ + h)) * S_ + s) * DK_ + dk] = f2bf(v);
                    } else {
                        ((uint16_t*)Cout)[(((size_t)(b * H_ + h)) * DK_ + dk) * S_ + s] = f2bf(v);
                    }
                }
            }
}

// ---------------- RoPE over contiguous q||k region, one pair/thread ----------------
__global__ __launch_bounds__(256) void rope_kernel(uint16_t* __restrict__ a,
                                                   const int* __restrict__ pos,
                                                   int npairs) {
    int t = blockIdx.x * 256 + threadIdx.x;
    if (t >= npairs) return;
    int j = t & 31;
    int s = (t >> 5) & (S_ - 1);
    float p   = (float)pos[s];
    float inv = exp2f(-(float)j * (13.287712379549449f / 32.0f));
    float ang = p * inv;
    float sn, c;
    sincosf(ang, &sn, &c);
    uint32_t pr = *reinterpret_cast<uint32_t*>(a + (size_t)2 * t);
    float x0 = bf2f((uint16_t)(pr & 0xFFFF));
    float x1 = bf2f((uint16_t)(pr >> 16));
    float r0 = x0 * c - x1 * sn;
    float r1 = x0 * sn + x1 * c;
    uint32_t ot = (uint32_t)f2bf(r0) | ((uint32_t)f2bf(r1) << 16);
    *reinterpret_cast<uint32_t*>(a + (size_t)2 * t) = ot;
}

// ---------------- causal flash attention, work-balanced ----------------
// grid 1024 = (16 pair-tiles x 64 bh). Block does q-supertile pr and 31-pr
// (uniform 33 k-tiles of 64). 4 waves x 16 q-rows, k-tile = 64.
__global__ __launch_bounds__(256) void flash_attn(const uint16_t* __restrict__ q,
                                                  const uint16_t* __restrict__ k,
                                                  const uint16_t* __restrict__ vt,
                                                  uint16_t* __restrict__ attn) {
    __shared__ uint16_t pbuf[4][16][64];
    const int lane = threadIdx.x & 63;
    const int w    = threadIdx.x >> 6;
    const int lr   = lane & 15, lg = lane >> 4;
    const int bh   = blockIdx.x >> 4;
    const int pr   = blockIdx.x & 15;
    const int b    = bh >> 4, h = bh & 15;

    const uint16_t* kb = k  + (size_t)bh * S_ * DK_;
    const uint16_t* vb = vt + (size_t)bh * DK_ * S_;

    for (int pass = 0; pass < 2; ++pass) {
        const int qt = pass ? (31 - pr) : pr;
        const int q0 = qt * 64 + w * 16;
        const uint16_t* qb = q + ((size_t)bh * S_ + q0) * DK_;
        s16x8 qf0 = *reinterpret_cast<const s16x8*>(qb + (size_t)lr * DK_ + lg * 8);
        s16x8 qf1 = *reinterpret_cast<const s16x8*>(qb + (size_t)lr * DK_ + 32 + lg * 8);

        f32x4 o[4] = {};
        float mrow[4], lrow[4];
#pragma unroll
        for (int r = 0; r < 4; ++r) { mrow[r] = -3e38f; lrow[r] = 0.f; }

        const int kend = q0 + 16;
        for (int kt = 0; kt < kend; kt += 64) {
            f32x4 sc[4] = {};
            __builtin_amdgcn_s_setprio(1);
#pragma unroll
            for (int ct = 0; ct < 4; ++ct) {
                const uint16_t* kp = kb + (size_t)(kt + ct * 16 + lr) * DK_ + lg * 8;
                s16x8 kf0 = *reinterpret_cast<const s16x8*>(kp);
                s16x8 kf1 = *reinterpret_cast<const s16x8*>(kp + 32);
                sc[ct] = __builtin_amdgcn_mfma_f32_16x16x32_bf16(qf0, kf0, sc[ct], 0, 0, 0);
                sc[ct] = __builtin_amdgcn_mfma_f32_16x16x32_bf16(qf1, kf1, sc[ct], 0, 0, 0);
            }
            __builtin_amdgcn_s_setprio(0);

            const bool need_mask = (kt + 63 > q0);
            float sv[4][4];
#pragma unroll
            for (int ct = 0; ct < 4; ++ct)
#pragma unroll
                for (int r = 0; r < 4; ++r) {
                    float v = sc[ct][r] * 0.125f;   // 1/sqrt(64)
                    if (need_mask) {
                        int colg = kt + ct * 16 + lr;
                        int rowg = q0 + lg * 4 + r;
                        if (colg > rowg) v = -3e38f;
                    }
                    sv[ct][r] = v;
                }

#pragma unroll
            for (int r = 0; r < 4; ++r) {
                float tm = fmaxf(fmaxf(sv[0][r], sv[1][r]), fmaxf(sv[2][r], sv[3][r]));
#pragma unroll
                for (int off = 1; off < 16; off <<= 1)
                    tm = fmaxf(tm, __shfl_xor(tm, off));
                float mnew  = fmaxf(mrow[r], tm);
                float alpha = __expf(mrow[r] - mnew);
                mrow[r] = mnew;
                float p0 = __expf(sv[0][r] - mnew);
                float p1 = __expf(sv[1][r] - mnew);
                float p2 = __expf(sv[2][r] - mnew);
                float p3 = __expf(sv[3][r] - mnew);
                float ps = (p0 + p1) + (p2 + p3);
#pragma unroll
                for (int off = 1; off < 16; off <<= 1)
                    ps += __shfl_xor(ps, off);
                lrow[r] = lrow[r] * alpha + ps;
#pragma unroll
                for (int j = 0; j < 4; ++j) o[j][r] *= alpha;
                pbuf[w][lg * 4 + r][lr]      = f2bf(p0);
                pbuf[w][lg * 4 + r][16 + lr] = f2bf(p1);
                pbuf[w][lg * 4 + r][32 + lr] = f2bf(p2);
                pbuf[w][lg * 4 + r][48 + lr] = f2bf(p3);
            }

            // PV (same-wave DS ops are ordered; pbuf is wave-private)
            s16x8 pa0 = *reinterpret_cast<const s16x8*>(&pbuf[w][lr][lg * 8]);
            s16x8 pa1 = *reinterpret_cast<const s16x8*>(&pbuf[w][lr][32 + lg * 8]);
            __builtin_amdgcn_s_setprio(1);
#pragma unroll
            for (int j = 0; j < 4; ++j) {
                const uint16_t* vp = vb + (size_t)(j * 16 + lr) * S_ + kt;
                s16x8 vf0 = *reinterpret_cast<const s16x8*>(vp + lg * 8);
                s16x8 vf1 = *reinterpret_cast<const s16x8*>(vp + 32 + lg * 8);
                o[j] = __builtin_amdgcn_mfma_f32_16x16x32_bf16(pa0, vf0, o[j], 0, 0, 0);
                o[j] = __builtin_amdgcn_mfma_f32_16x16x32_bf16(pa1, vf1, o[j], 0, 0, 0);
            }
            __builtin_amdgcn_s_setprio(0);
        }

        float rinv[4];
#pragma unroll
        for (int r = 0; r < 4; ++r) rinv[r] = 1.0f / lrow[r];
#pragma unroll
        for (int j = 0; j < 4; ++j)
#pragma unroll
            for (int r = 0; r < 4; ++r) {
                int sg = q0 + lg * 4 + r;
                attn[((size_t)b * S_ + sg) * DM_ + h * 64 + j * 16 + lr] = f2bf(o[j][r] * rinv[r]);
            }
    }
}

extern "C" void kernel_launch(void* const* d_in, const int* in_sizes, int n_in,
                              void* d_out, int out_size, void* d_ws, size_t ws_size,
                              hipStream_t stream) {
    (void)in_sizes; (void)n_in; (void)out_size;
    const float* x   = (const float*)d_in[0];
    const float* wq  = (const float*)d_in[1];
    const float* wk  = (const float*)d_in[2];
    const float* wv  = (const float*)d_in[3];
    const float* wo  = (const float*)d_in[4];
    const int* tpos  = (const int*)d_in[5];
    float* out = (float*)d_out;

    const size_t NX = (size_t)M_ * DM_;   // 8388608
    const size_t NW = (size_t)DM_ * DM_;  // 1048576
    const size_t need = (NX + 4 * NW + 4 * NX) * sizeof(uint16_t);
    if (ws_size < need) return;  // fail loudly via wrong output

    uint16_t* ws  = (uint16_t*)d_ws;
    uint16_t* xb  = ws;
    uint16_t* wqb = xb + NX;
    uint16_t* wkb = wqb + NW;
    uint16_t* wvb = wkb + NW;
    uint16_t* wob = wvb + NW;
    uint16_t* qb  = wob + NW;
    uint16_t* kb  = qb + NX;    // contiguous with qb (rope covers both)
    uint16_t* vtb = kb + NX;
    uint16_t* ab  = vtb + NX;

    cvt_bf16<<<(int)(NX / 1024), 256, 0, stream>>>(x, xb, (int)NX);
    cvt_bf16<<<(int)(NW / 1024), 256, 0, stream>>>(wq, wqb, (int)NW);
    cvt_bf16<<<(int)(NW / 1024), 256, 0, stream>>>(wk, wkb, (int)NW);
    cvt_bf16<<<(int)(NW / 1024), 256, 0, stream>>>(wv, wvb, (int)NW);
    cvt_bf16<<<(int)(NW / 1024), 256, 0, stream>>>(wo, wob, (int)NW);

    dim3 g(M_ / 128, DM_ / 128), blk(256);
    gemm_bt<1><<<g, blk, 0, stream>>>(xb, wqb, qb,  M_, DM_, DM_);
    gemm_bt<1><<<g, blk, 0, stream>>>(xb, wkb, kb,  M_, DM_, DM_);
    gemm_bt<2><<<g, blk, 0, stream>>>(xb, wvb, vtb, M_, DM_, DM_);

    int npairs = 2 * B_ * H_ * S_ * (DK_ / 2);   // q and k together
    rope_kernel<<<npairs / 256, 256, 0, stream>>>(qb, tpos, npairs);

    flash_attn<<<dim3(16 * B_ * H_), 256, 0, stream>>>(qb, kb, vtb, ab);

    gemm_bt<0><<<g, blk, 0, stream>>>(ab, wob, out, M_, DM_, DM_);
}